// Round 6
// baseline (374.684 us; speedup 1.0000x reference)
//
#include <hip/hip_runtime.h>
#include <stdint.h>

#define B 32
#define P 24564      // divisible by 4
#define NCLS 21
#define NOBJ 24
#define THRESH 0.5f
#define NBKT 2048    // level-0/1 histogram buckets
#define LCAP 2816    // LDS candidate-list capacity

// ws layout (bytes), total 3,504,928
#define OFF_ACC      0        // double[3]: loc_sum, conf_pos, conf_neg
#define OFF_ARRVALL  24       // u32: global arrival counter
#define OFF_BARRV    32       // u32[B]: per-batch arrival counters
#define OFF_NPOS     160      // int[B]
#define HDR_WORDS    72       // 288 B header, zeroed by k_objmax block(0,0)
#define OFF_OBJPART  288      // u64[B*NOBJ*16] = 98304 (per-block partials, no init)
#define OFF_HIST     98592    // u32[B*NBKT] = 262144 (zeroed by k_objmax slices)
#define OFF_CENEG    360736   // float[B*P] = 3144192 (16B aligned)

typedef unsigned long long u64;
__device__ __forceinline__ u64 umax64(u64 a, u64 b) { return a > b ? a : b; }

// ---------------- Kernel 1: per-object best-prior partials + ws init -------------------------
__global__ __launch_bounds__(256) void k_objmax(
    const float* __restrict__ gt_boxes, const float* __restrict__ anchor,
    char* __restrict__ ws) {
#pragma clang fp contract(off)
    int b = blockIdx.y;
    int j = blockIdx.x;                       // 0..15
    int tid = threadIdx.x;
    unsigned* hist = (unsigned*)(ws + OFF_HIST);
    u64* part = (u64*)(ws + OFF_OBJPART);
    if (tid < 128) hist[(b * 16 + j) * 128 + tid] = 0u;      // zero hist slice
    if (b == 0 && j == 0 && tid < HDR_WORDS) ((unsigned*)ws)[tid] = 0u;  // zero header
    __shared__ float4 sbox[NOBJ];
    __shared__ u64 sbest[NOBJ];
    if (tid < NOBJ) {
        const float* g = gt_boxes + (size_t)(b * NOBJ + tid) * 4;
        sbox[tid] = make_float4(g[0], g[1], g[2], g[3]);
        sbest[tid] = 0ull;
    }
    __syncthreads();
    u64 best[NOBJ];
#pragma unroll
    for (int n = 0; n < NOBJ; n++) best[n] = 0ull;
    int pend = min(P, (j + 1) * 1536);
    for (int p = j * 1536 + tid; p < pend; p += 256) {
        float4 a = *(const float4*)(anchor + (size_t)p * 4);
        float ax0 = a.x - a.z * 0.5f, ay0 = a.y - a.w * 0.5f;
        float ax1 = a.x + a.z * 0.5f, ay1 = a.y + a.w * 0.5f;
        float area_a = (ax1 - ax0) * (ay1 - ay0);
        unsigned pk = ~(unsigned)p;
#pragma unroll
        for (int n = 0; n < NOBJ; n++) {
            float4 bx = sbox[n];
            float ltx = fmaxf(bx.x, ax0), lty = fmaxf(bx.y, ay0);
            float rbx = fminf(bx.z, ax1), rby = fminf(bx.w, ay1);
            float w = fmaxf(rbx - ltx, 0.f), h = fmaxf(rby - lty, 0.f);
            float inter = w * h;
            float area_o = (bx.z - bx.x) * (bx.w - bx.y);
            float iou = inter / (area_o + area_a - inter);
            u64 key = ((u64)__float_as_uint(iou) << 32) | pk;
            best[n] = umax64(best[n], key);
        }
    }
#pragma unroll
    for (int n = 0; n < NOBJ; n++) {
        u64 v = best[n];
        for (int off = 32; off > 0; off >>= 1) v = umax64(v, __shfl_down(v, off, 64));
        if ((tid & 63) == 0) atomicMax(&sbest[n], v);
    }
    __syncthreads();
    if (tid < NOBJ) part[((size_t)b * NOBJ + tid) * 16 + j] = sbest[tid];  // plain store
}

// ---- parallel boundary-bucket find: suffix-scan of shist[NB], writes sscal[0]=bkt, [1]=resid
__device__ __forceinline__ void find_bound(const unsigned* shist, int NB, int K,
                                           int* sscal, unsigned* wsum, int tid) {
    int G = NB >> 8;
    unsigned loc[8];
    unsigned tot = 0;
    for (int g = 0; g < G; g++) { loc[g] = shist[tid * G + g]; tot += loc[g]; }
    unsigned v = tot;
    int lane = tid & 63;
    for (int off = 1; off < 64; off <<= 1) {
        unsigned o = __shfl_down(v, off, 64);
        if (lane + off < 64) v += o;     // v = inclusive suffix within wave
    }
    if (lane == 0) wsum[tid >> 6] = v;
    __syncthreads();
    unsigned above = 0;
    for (int w = (tid >> 6) + 1; w < 4; w++) above += wsum[w];
    unsigned sfx_excl = above + (v - tot);   // suffix over threads > tid
    unsigned snext = 0, sloc = 0;
    for (int k = G - 1; k >= 0; k--) {
        sloc = snext + loc[k];
        unsigned sfx_i = sloc + sfx_excl;
        unsigned sfx_n = snext + sfx_excl;
        if (sfx_i >= (unsigned)K && sfx_n < (unsigned)K) {
            sscal[0] = tid * G + k;
            sscal[1] = K - (int)sfx_n;
        }
        snext = sloc;
    }
    if (tid == 0) {
        unsigned total = sloc + sfx_excl;
        if (total < (unsigned)K) {        // take everything + zero padding
            sscal[0] = 0;
            sscal[1] = K - (int)((sloc - loc[0]) + sfx_excl);
        }
    }
    __syncthreads();
}

// ---------------- Kernel 2: fused match+CE+hist, per-batch last-arriver select ---------------
__global__ __launch_bounds__(256) void k_fused(
    const float* __restrict__ pred_cls, const float* __restrict__ pred_loc,
    const float* __restrict__ gt_boxes, const int* __restrict__ gt_labels,
    const float* __restrict__ anchor, char* __restrict__ ws, float* __restrict__ out) {
#pragma clang fp contract(off)
    double* acc = (double*)(ws + OFF_ACC);
    unsigned* arrv_all = (unsigned*)(ws + OFF_ARRVALL);
    unsigned* batch_arrv = (unsigned*)(ws + OFF_BARRV);
    int* n_pos = (int*)(ws + OFF_NPOS);
    const u64* objpart = (const u64*)(ws + OFF_OBJPART);
    unsigned* hist = (unsigned*)(ws + OFF_HIST);
    float* ce_neg = (float*)(ws + OFF_CENEG);

    __shared__ float4 sbox[NOBJ];
    __shared__ int slab[NOBJ];
    __shared__ int sobj[NOBJ];
    __shared__ unsigned shist[NBKT];     // 8 KB, reused per level
    __shared__ unsigned slist[LCAP];     // 11 KB
    __shared__ unsigned list2[LCAP];     // 11 KB
    __shared__ float swf[8];
    __shared__ int swi[4];
    __shared__ double swd[4];
    __shared__ unsigned wsum[4];
    __shared__ int sscal[4];             // [0]=bkt [1]=resid [2]=cnt1 [3]=cnt2

    const int tid = threadIdx.x;
    const int b = blockIdx.x / 24;
    const int j = blockIdx.x % 24;

    // ---- Phase A: reduce per-object partials, load boxes/labels ----
    for (int i = tid; i < NBKT; i += 256) shist[i] = 0u;
    if (tid < NOBJ) {
        const float* g = gt_boxes + (size_t)(b * NOBJ + tid) * 4;
        sbox[tid] = make_float4(g[0], g[1], g[2], g[3]);
        slab[tid] = gt_labels[b * NOBJ + tid];
        const u64* pp = objpart + ((size_t)b * NOBJ + tid) * 16;
        u64 m = pp[0];
#pragma unroll
        for (int q = 1; q < 16; q++) m = umax64(m, pp[q]);
        sobj[tid] = (int)(~(unsigned)(m & 0xFFFFFFFFull));
    }
    __syncthreads();

    // ---- Phase B: match + loc-L1 + CE + LDS histogram (register streaming, 4 priors/thread)
    int p0 = j * 1024 + tid * 4;
    float lsum = 0.f, cpos = 0.f;
    int lnp = 0;
    if (p0 < P) {
        float4 xx[21];
        const float4* xp = (const float4*)(pred_cls + ((size_t)b * P + p0) * NCLS);
#pragma unroll
        for (int k = 0; k < 21; k++) xx[k] = xp[k];
        const float* arr = (const float*)xx;
        float4 anc4[4];
#pragma unroll
        for (int r = 0; r < 4; r++) anc4[r] = ((const float4*)anchor)[p0 + r];
        float4 cev;
        float* cevp = (float*)&cev;
#pragma unroll
        for (int r = 0; r < 4; r++) {
            int p = p0 + r;
            float4 a = anc4[r];
            float ax0 = a.x - a.z * 0.5f, ay0 = a.y - a.w * 0.5f;
            float ax1 = a.x + a.z * 0.5f, ay1 = a.y + a.w * 0.5f;
            float area_a = (ax1 - ax0) * (ay1 - ay0);
            float bv = -1.f;
            int bn = 0;
#pragma unroll
            for (int n = 0; n < NOBJ; n++) {
                float4 bx = sbox[n];
                float ltx = fmaxf(bx.x, ax0), lty = fmaxf(bx.y, ay0);
                float rbx = fminf(bx.z, ax1), rby = fminf(bx.w, ay1);
                float w = fmaxf(rbx - ltx, 0.f), h = fmaxf(rby - lty, 0.f);
                float inter = w * h;
                float area_o = (bx.z - bx.x) * (bx.w - bx.y);
                float iou = inter / (area_o + area_a - inter);
                if (p == sobj[n]) iou = 1.0f;
                if (iou > bv) { bv = iou; bn = n; }
            }
            int pos = (bv >= THRESH) ? 1 : 0;
            int cls = pos ? (slab[bn] + 1) : 0;
            const float* x = arr + r * 21;
            float m = x[0];
#pragma unroll
            for (int q = 1; q < NCLS; q++) m = fmaxf(m, x[q]);
            float s = 0.f;
#pragma unroll
            for (int q = 0; q < NCLS; q++) s += __expf(x[q] - m);
            float xc = x[0];
#pragma unroll
            for (int q = 1; q < NCLS; q++) xc = (cls == q) ? x[q] : xc;
            float ce = m + __logf(s) - xc;
            if (pos) {
                lnp++;
                cpos += ce;
                cevp[r] = 0.f;
                float4 bx = sbox[bn];
                float bcx = (bx.x + bx.z) * 0.5f, bcy = (bx.y + bx.w) * 0.5f;
                float bw = bx.z - bx.x, bh = bx.w - bx.y;
                float t0 = (bcx - a.x) / (a.z / 10.0f);
                float t1 = (bcy - a.y) / (a.w / 10.0f);
                float t2 = __logf(bw / a.z) * 5.0f;
                float t3 = __logf(bh / a.w) * 5.0f;
                float4 pl = *(const float4*)(pred_loc + ((size_t)b * P + p) * 4);
                lsum += fabsf(pl.x - t0) + fabsf(pl.y - t1) + fabsf(pl.z - t2) + fabsf(pl.w - t3);
            } else {
                float cen = fmaxf(ce, 0.f);   // guard: keep sign bit out of bucket bits
                cevp[r] = cen;
                atomicAdd(&shist[__float_as_uint(cen) >> 20], 1u);
            }
        }
        *(float4*)(ce_neg + (size_t)b * P + p0) = cev;
    }
    for (int off = 32; off > 0; off >>= 1) {
        lsum += __shfl_down(lsum, off, 64);
        cpos += __shfl_down(cpos, off, 64);
        lnp  += __shfl_down(lnp, off, 64);
    }
    if ((tid & 63) == 0) { swf[tid >> 6] = lsum; swf[4 + (tid >> 6)] = cpos; swi[tid >> 6] = lnp; }
    __syncthreads();
    if (tid == 0) {
        float ls = swf[0] + swf[1] + swf[2] + swf[3];
        float cs = swf[4] + swf[5] + swf[6] + swf[7];
        int np = swi[0] + swi[1] + swi[2] + swi[3];
        if (np) atomicAdd(&n_pos[b], np);
        atomicAdd(&acc[0], (double)ls);
        atomicAdd(&acc[1], (double)cs);
    }
    for (int i = tid; i < NBKT; i += 256) {
        unsigned c = shist[i];
        if (c) atomicAdd(&hist[b * NBKT + i], c);
    }

    // ---- per-batch arrival: last of 24 blocks becomes the selector ----
    __syncthreads();
    if (tid == 0) {
        __threadfence();   // release: write back this XCD's dirty L2 (ce_neg stores)
        unsigned old = __hip_atomic_fetch_add(&batch_arrv[b], 1u,
                                              __ATOMIC_ACQ_REL, __HIP_MEMORY_SCOPE_AGENT);
        swi[0] = (old == 23) ? 1 : 0;
    }
    __syncthreads();
    if (swi[0] == 0) return;

    // ---- Phase C (winner only): exact hard-negative top-K sum via 3-level radix refine ----
    int npb = __hip_atomic_load(&n_pos[b], __ATOMIC_RELAXED, __HIP_MEMORY_SCOPE_AGENT);
    int K = npb * 3;
    if (K > P) K = P;
    double s = 0.0;
    if (K > 0) {
        for (int i = tid; i < NBKT; i += 256)
            shist[i] = __hip_atomic_load(&hist[b * NBKT + i],
                                         __ATOMIC_RELAXED, __HIP_MEMORY_SCOPE_AGENT);
        __syncthreads();
        find_bound(shist, NBKT, K, sscal, wsum, tid);
        int b0 = sscal[0], Kp0 = sscal[1];
        if (tid == 0) sscal[2] = 0;
        __syncthreads();
        const uint4* x4 = (const uint4*)(ce_neg + (size_t)b * P);
        for (int i = tid; i < P / 4; i += 256) {
            uint4 v = x4[i];
            unsigned vv[4] = {v.x, v.y, v.z, v.w};
#pragma unroll
            for (int r = 0; r < 4; r++) {
                int bk = (int)(vv[r] >> 20);
                if (bk > b0) s += (double)__uint_as_float(vv[r]);
                else if (bk == b0) {
                    int pos = atomicAdd(&sscal[2], 1);
                    if (pos < LCAP) slist[pos] = vv[r];
                }
            }
        }
        __syncthreads();
        int lcnt = sscal[2];
        if (Kp0 > 0) {
            if (lcnt <= LCAP) {
                // level 1: bits [9:20)
                for (int i = tid; i < NBKT; i += 256) shist[i] = 0u;
                __syncthreads();
                for (int i = tid; i < lcnt; i += 256)
                    atomicAdd(&shist[(slist[i] >> 9) & 0x7FFu], 1u);
                __syncthreads();
                find_bound(shist, NBKT, Kp0, sscal, wsum, tid);
                int b1 = sscal[0], Kp1 = sscal[1];
                if (tid == 0) sscal[3] = 0;
                __syncthreads();
                for (int i = tid; i < lcnt; i += 256) {
                    unsigned v = slist[i];
                    int sb = (int)((v >> 9) & 0x7FFu);
                    if (sb > b1) s += (double)__uint_as_float(v);
                    else if (sb == b1) list2[atomicAdd(&sscal[3], 1)] = v;
                }
                __syncthreads();
                int n2 = sscal[3];
                // level 2: bits [0:9)
                for (int i = tid; i < 512; i += 256) shist[i] = 0u;
                __syncthreads();
                for (int i = tid; i < n2; i += 256)
                    atomicAdd(&shist[list2[i] & 0x1FFu], 1u);
                __syncthreads();
                find_bound(shist, 512, Kp1, sscal, wsum, tid);
                int b2 = sscal[0], R = sscal[1];
                for (int i = tid; i < n2; i += 256) {
                    unsigned v = list2[i];
                    if ((int)(v & 0x1FFu) > b2) s += (double)__uint_as_float(v);
                }
                unsigned Tbits = ((unsigned)b0 << 20) | ((unsigned)b1 << 9) | (unsigned)b2;
                if (tid == 0) s += (double)R * (double)__uint_as_float(Tbits);
            } else {
                // fallback (never expected): 20-bit binary search over global, bucket-filtered
                const unsigned* src = (const unsigned*)(ce_neg + (size_t)b * P);
                unsigned T = (unsigned)b0 << 20;
                for (int bit = 19; bit >= 0; bit--) {
                    unsigned cand = T | (1u << bit);
                    int cc = 0;
                    for (int i = tid; i < P; i += 256) {
                        unsigned v = src[i];
                        if ((int)(v >> 20) == b0 && v >= cand) cc++;
                    }
                    for (int off = 32; off > 0; off >>= 1) cc += __shfl_down(cc, off, 64);
                    if ((tid & 63) == 0) swi[tid >> 6] = cc;
                    __syncthreads();
                    int tot = swi[0] + swi[1] + swi[2] + swi[3];
                    __syncthreads();
                    if (tot >= Kp0) T = cand;
                }
                int cgt = 0;
                for (int i = tid; i < P; i += 256) {
                    unsigned v = src[i];
                    if ((int)(v >> 20) == b0 && v > T) { cgt++; s += (double)__uint_as_float(v); }
                }
                for (int off = 32; off > 0; off >>= 1) cgt += __shfl_down(cgt, off, 64);
                if ((tid & 63) == 0) swi[tid >> 6] = cgt;
                __syncthreads();
                if (tid == 0) {
                    int cg = swi[0] + swi[1] + swi[2] + swi[3];
                    s += (double)(Kp0 - cg) * (double)__uint_as_float(T);
                }
                __syncthreads();
            }
        }
        for (int off = 32; off > 0; off >>= 1) s += __shfl_down(s, off, 64);
        if ((tid & 63) == 0) swd[tid >> 6] = s;
        __syncthreads();
        if (tid == 0) atomicAdd(&acc[2], swd[0] + swd[1] + swd[2] + swd[3]);
    }

    // ---- global arrival: last of 32 winners writes the outputs ----
    __syncthreads();
    if (tid == 0) {
        __threadfence();
        unsigned old = __hip_atomic_fetch_add(arrv_all, 1u,
                                              __ATOMIC_ACQ_REL, __HIP_MEMORY_SCOPE_AGENT);
        if (old == B - 1) {
            int npt = 0;
            for (int k = 0; k < B; k++)
                npt += __hip_atomic_load(&n_pos[k], __ATOMIC_RELAXED, __HIP_MEMORY_SCOPE_AGENT);
            u64 u0 = __hip_atomic_load((u64*)&acc[0], __ATOMIC_RELAXED, __HIP_MEMORY_SCOPE_AGENT);
            u64 u1 = __hip_atomic_load((u64*)&acc[1], __ATOMIC_RELAXED, __HIP_MEMORY_SCOPE_AGENT);
            u64 u2 = __hip_atomic_load((u64*)&acc[2], __ATOMIC_RELAXED, __HIP_MEMORY_SCOPE_AGENT);
            double a0 = __longlong_as_double((long long)u0);
            double a1 = __longlong_as_double((long long)u1);
            double a2 = __longlong_as_double((long long)u2);
            double npf = (double)npt;
            float conf = (float)((a1 + a2) / npf);
            float loc = 10.0f * (float)(a0 / (npf * 4.0));
            out[0] = conf + loc;
            out[1] = conf;
            out[2] = loc;
        }
    }
}

extern "C" void kernel_launch(void* const* d_in, const int* in_sizes, int n_in,
                              void* d_out, int out_size, void* d_ws, size_t ws_size,
                              hipStream_t stream) {
    const float* pred_cls = (const float*)d_in[0];
    const float* pred_loc = (const float*)d_in[1];
    const float* gt_boxes = (const float*)d_in[2];
    const int*   gt_labels = (const int*)d_in[3];
    const float* anchor   = (const float*)d_in[4];
    float* out = (float*)d_out;
    char* ws = (char*)d_ws;

    k_objmax<<<dim3(16, B), 256, 0, stream>>>(gt_boxes, anchor, ws);
    k_fused<<<24 * B, 256, 0, stream>>>(pred_cls, pred_loc, gt_boxes, gt_labels,
                                        anchor, ws, out);
}

// Round 7
// 372.553 us; speedup vs baseline: 1.0057x; 1.0057x over previous
//
#include <hip/hip_runtime.h>
#include <stdint.h>

#define B 32
#define P 24564      // divisible by 4
#define NCLS 21
#define NOBJ 24
#define THRESH 0.5f
#define NBKT 2048    // level-0/1 histogram buckets
#define LCAP 2816    // LDS candidate-list capacity

// ws layout (bytes), total 3,504,928
#define OFF_ACC      0        // double[3]: loc_sum, conf_pos, conf_neg
#define OFF_ARRVALL  24       // u32: global arrival counter
#define OFF_BARRV    32       // u32[B]: per-batch arrival counters
#define OFF_NPOS     160      // int[B]
#define HDR_WORDS    72       // 288 B header, zeroed by k_objmax block(0,0)
#define OFF_OBJPART  288      // u64[B*NOBJ*16] = 98304 (per-block partials, no init)
#define OFF_HIST     98592    // u32[B*NBKT] = 262144 (zeroed by k_objmax slices)
#define OFF_CENEG    360736   // float[B*P] = 3144192 (16B aligned)

typedef unsigned long long u64;
__device__ __forceinline__ u64 umax64(u64 a, u64 b) { return a > b ? a : b; }

// ---------------- Kernel 1: per-object best-prior partials + ws init -------------------------
__global__ __launch_bounds__(256) void k_objmax(
    const float* __restrict__ gt_boxes, const float* __restrict__ anchor,
    char* __restrict__ ws) {
#pragma clang fp contract(off)
    int b = blockIdx.y;
    int j = blockIdx.x;                       // 0..15
    int tid = threadIdx.x;
    unsigned* hist = (unsigned*)(ws + OFF_HIST);
    u64* part = (u64*)(ws + OFF_OBJPART);
    if (tid < 128) hist[(b * 16 + j) * 128 + tid] = 0u;      // zero hist slice
    if (b == 0 && j == 0 && tid < HDR_WORDS) ((unsigned*)ws)[tid] = 0u;  // zero header
    __shared__ float4 sbox[NOBJ];
    __shared__ u64 sbest[NOBJ];
    if (tid < NOBJ) {
        const float* g = gt_boxes + (size_t)(b * NOBJ + tid) * 4;
        sbox[tid] = make_float4(g[0], g[1], g[2], g[3]);
        sbest[tid] = 0ull;
    }
    __syncthreads();
    u64 best[NOBJ];
#pragma unroll
    for (int n = 0; n < NOBJ; n++) best[n] = 0ull;
    int pend = min(P, (j + 1) * 1536);
    for (int p = j * 1536 + tid; p < pend; p += 256) {
        float4 a = *(const float4*)(anchor + (size_t)p * 4);
        float ax0 = a.x - a.z * 0.5f, ay0 = a.y - a.w * 0.5f;
        float ax1 = a.x + a.z * 0.5f, ay1 = a.y + a.w * 0.5f;
        float area_a = (ax1 - ax0) * (ay1 - ay0);
        unsigned pk = ~(unsigned)p;
#pragma unroll
        for (int n = 0; n < NOBJ; n++) {
            float4 bx = sbox[n];
            float ltx = fmaxf(bx.x, ax0), lty = fmaxf(bx.y, ay0);
            float rbx = fminf(bx.z, ax1), rby = fminf(bx.w, ay1);
            float w = fmaxf(rbx - ltx, 0.f), h = fmaxf(rby - lty, 0.f);
            float inter = w * h;
            float area_o = (bx.z - bx.x) * (bx.w - bx.y);
            float iou = inter / (area_o + area_a - inter);
            u64 key = ((u64)__float_as_uint(iou) << 32) | pk;
            best[n] = umax64(best[n], key);
        }
    }
#pragma unroll
    for (int n = 0; n < NOBJ; n++) {
        u64 v = best[n];
        for (int off = 32; off > 0; off >>= 1) v = umax64(v, __shfl_down(v, off, 64));
        if ((tid & 63) == 0) atomicMax(&sbest[n], v);
    }
    __syncthreads();
    if (tid < NOBJ) part[((size_t)b * NOBJ + tid) * 16 + j] = sbest[tid];  // plain store
}

// ---- parallel boundary-bucket find: suffix-scan of shist[NB], writes sscal[0]=bkt, [1]=resid
__device__ __forceinline__ void find_bound(const unsigned* shist, int NB, int K,
                                           int* sscal, unsigned* wsum, int tid) {
    int G = NB >> 8;
    unsigned loc[8];
    unsigned tot = 0;
    for (int g = 0; g < G; g++) { loc[g] = shist[tid * G + g]; tot += loc[g]; }
    unsigned v = tot;
    int lane = tid & 63;
    for (int off = 1; off < 64; off <<= 1) {
        unsigned o = __shfl_down(v, off, 64);
        if (lane + off < 64) v += o;     // v = inclusive suffix within wave
    }
    if (lane == 0) wsum[tid >> 6] = v;
    __syncthreads();
    unsigned above = 0;
    for (int w = (tid >> 6) + 1; w < 4; w++) above += wsum[w];
    unsigned sfx_excl = above + (v - tot);   // suffix over threads > tid
    unsigned snext = 0, sloc = 0;
    for (int k = G - 1; k >= 0; k--) {
        sloc = snext + loc[k];
        unsigned sfx_i = sloc + sfx_excl;
        unsigned sfx_n = snext + sfx_excl;
        if (sfx_i >= (unsigned)K && sfx_n < (unsigned)K) {
            sscal[0] = tid * G + k;
            sscal[1] = K - (int)sfx_n;
        }
        snext = sloc;
    }
    if (tid == 0) {
        unsigned total = sloc + sfx_excl;
        if (total < (unsigned)K) {        // take everything + zero padding
            sscal[0] = 0;
            sscal[1] = K - (int)((sloc - loc[0]) + sfx_excl);
        }
    }
    __syncthreads();
}

// ---------------- Kernel 2: fused match+CE+hist, per-batch last-arriver select ---------------
// __launch_bounds__(256, 2): VGPR cap 256 so the 21-float4 class-score array stays in
// registers. R6 regression root-cause: default bounds capped VGPR at 88 -> full spill of
// the 336 B/thread array to scratch (dur 277us, VALUBusy 8%). Do NOT remove the ",2".
__global__ __launch_bounds__(256, 2) void k_fused(
    const float* __restrict__ pred_cls, const float* __restrict__ pred_loc,
    const float* __restrict__ gt_boxes, const int* __restrict__ gt_labels,
    const float* __restrict__ anchor, char* __restrict__ ws, float* __restrict__ out) {
#pragma clang fp contract(off)
    double* acc = (double*)(ws + OFF_ACC);
    unsigned* arrv_all = (unsigned*)(ws + OFF_ARRVALL);
    unsigned* batch_arrv = (unsigned*)(ws + OFF_BARRV);
    int* n_pos = (int*)(ws + OFF_NPOS);
    const u64* objpart = (const u64*)(ws + OFF_OBJPART);
    unsigned* hist = (unsigned*)(ws + OFF_HIST);
    float* ce_neg = (float*)(ws + OFF_CENEG);

    __shared__ float4 sbox[NOBJ];
    __shared__ int slab[NOBJ];
    __shared__ int sobj[NOBJ];
    __shared__ unsigned shist[NBKT];     // 8 KB, reused per level
    __shared__ unsigned slist[LCAP];     // 11 KB
    __shared__ unsigned list2[LCAP];     // 11 KB
    __shared__ float swf[8];
    __shared__ int swi[4];
    __shared__ double swd[4];
    __shared__ unsigned wsum[4];
    __shared__ int sscal[4];             // [0]=bkt [1]=resid [2]=cnt1 [3]=cnt2

    const int tid = threadIdx.x;
    const int b = blockIdx.x / 24;
    const int j = blockIdx.x % 24;

    // ---- Phase A: reduce per-object partials, load boxes/labels ----
    for (int i = tid; i < NBKT; i += 256) shist[i] = 0u;
    if (tid < NOBJ) {
        const float* g = gt_boxes + (size_t)(b * NOBJ + tid) * 4;
        sbox[tid] = make_float4(g[0], g[1], g[2], g[3]);
        slab[tid] = gt_labels[b * NOBJ + tid];
        const u64* pp = objpart + ((size_t)b * NOBJ + tid) * 16;
        u64 m = pp[0];
#pragma unroll
        for (int q = 1; q < 16; q++) m = umax64(m, pp[q]);
        sobj[tid] = (int)(~(unsigned)(m & 0xFFFFFFFFull));
    }
    __syncthreads();

    // ---- Phase B: match + loc-L1 + CE + LDS histogram (register streaming, 4 priors/thread)
    int p0 = j * 1024 + tid * 4;
    float lsum = 0.f, cpos = 0.f;
    int lnp = 0;
    if (p0 < P) {
        float4 xx[21];
        const float4* xp = (const float4*)(pred_cls + ((size_t)b * P + p0) * NCLS);
#pragma unroll
        for (int k = 0; k < 21; k++) xx[k] = xp[k];
        const float* arr = (const float*)xx;
        float4 anc4[4];
#pragma unroll
        for (int r = 0; r < 4; r++) anc4[r] = ((const float4*)anchor)[p0 + r];
        float4 cev;
        float* cevp = (float*)&cev;
#pragma unroll
        for (int r = 0; r < 4; r++) {
            int p = p0 + r;
            float4 a = anc4[r];
            float ax0 = a.x - a.z * 0.5f, ay0 = a.y - a.w * 0.5f;
            float ax1 = a.x + a.z * 0.5f, ay1 = a.y + a.w * 0.5f;
            float area_a = (ax1 - ax0) * (ay1 - ay0);
            float bv = -1.f;
            int bn = 0;
#pragma unroll
            for (int n = 0; n < NOBJ; n++) {
                float4 bx = sbox[n];
                float ltx = fmaxf(bx.x, ax0), lty = fmaxf(bx.y, ay0);
                float rbx = fminf(bx.z, ax1), rby = fminf(bx.w, ay1);
                float w = fmaxf(rbx - ltx, 0.f), h = fmaxf(rby - lty, 0.f);
                float inter = w * h;
                float area_o = (bx.z - bx.x) * (bx.w - bx.y);
                float iou = inter / (area_o + area_a - inter);
                if (p == sobj[n]) iou = 1.0f;
                if (iou > bv) { bv = iou; bn = n; }
            }
            int pos = (bv >= THRESH) ? 1 : 0;
            int cls = pos ? (slab[bn] + 1) : 0;
            const float* x = arr + r * 21;
            float m = x[0];
#pragma unroll
            for (int q = 1; q < NCLS; q++) m = fmaxf(m, x[q]);
            float s = 0.f;
#pragma unroll
            for (int q = 0; q < NCLS; q++) s += __expf(x[q] - m);
            float xc = x[0];
#pragma unroll
            for (int q = 1; q < NCLS; q++) xc = (cls == q) ? x[q] : xc;
            float ce = m + __logf(s) - xc;
            if (pos) {
                lnp++;
                cpos += ce;
                cevp[r] = 0.f;
                float4 bx = sbox[bn];
                float bcx = (bx.x + bx.z) * 0.5f, bcy = (bx.y + bx.w) * 0.5f;
                float bw = bx.z - bx.x, bh = bx.w - bx.y;
                float t0 = (bcx - a.x) / (a.z / 10.0f);
                float t1 = (bcy - a.y) / (a.w / 10.0f);
                float t2 = __logf(bw / a.z) * 5.0f;
                float t3 = __logf(bh / a.w) * 5.0f;
                float4 pl = *(const float4*)(pred_loc + ((size_t)b * P + p) * 4);
                lsum += fabsf(pl.x - t0) + fabsf(pl.y - t1) + fabsf(pl.z - t2) + fabsf(pl.w - t3);
            } else {
                float cen = fmaxf(ce, 0.f);   // guard: keep sign bit out of bucket bits
                cevp[r] = cen;
                atomicAdd(&shist[__float_as_uint(cen) >> 20], 1u);
            }
        }
        *(float4*)(ce_neg + (size_t)b * P + p0) = cev;
    }
    for (int off = 32; off > 0; off >>= 1) {
        lsum += __shfl_down(lsum, off, 64);
        cpos += __shfl_down(cpos, off, 64);
        lnp  += __shfl_down(lnp, off, 64);
    }
    if ((tid & 63) == 0) { swf[tid >> 6] = lsum; swf[4 + (tid >> 6)] = cpos; swi[tid >> 6] = lnp; }
    __syncthreads();
    if (tid == 0) {
        float ls = swf[0] + swf[1] + swf[2] + swf[3];
        float cs = swf[4] + swf[5] + swf[6] + swf[7];
        int np = swi[0] + swi[1] + swi[2] + swi[3];
        if (np) atomicAdd(&n_pos[b], np);
        atomicAdd(&acc[0], (double)ls);
        atomicAdd(&acc[1], (double)cs);
    }
    for (int i = tid; i < NBKT; i += 256) {
        unsigned c = shist[i];
        if (c) atomicAdd(&hist[b * NBKT + i], c);
    }

    // ---- per-batch arrival: last of 24 blocks becomes the selector ----
    __syncthreads();
    if (tid == 0) {
        __threadfence();   // release: write back dirty lines (ce_neg stores)
        unsigned old = __hip_atomic_fetch_add(&batch_arrv[b], 1u,
                                              __ATOMIC_ACQ_REL, __HIP_MEMORY_SCOPE_AGENT);
        swi[0] = (old == 23) ? 1 : 0;
    }
    __syncthreads();
    if (swi[0] == 0) return;

    // ---- Phase C (winner only): exact hard-negative top-K sum via 3-level radix refine ----
    int npb = __hip_atomic_load(&n_pos[b], __ATOMIC_RELAXED, __HIP_MEMORY_SCOPE_AGENT);
    int K = npb * 3;
    if (K > P) K = P;
    double s = 0.0;
    if (K > 0) {
        for (int i = tid; i < NBKT; i += 256)
            shist[i] = __hip_atomic_load(&hist[b * NBKT + i],
                                         __ATOMIC_RELAXED, __HIP_MEMORY_SCOPE_AGENT);
        __syncthreads();
        find_bound(shist, NBKT, K, sscal, wsum, tid);
        int b0 = sscal[0], Kp0 = sscal[1];
        if (tid == 0) sscal[2] = 0;
        __syncthreads();
        const uint4* x4 = (const uint4*)(ce_neg + (size_t)b * P);
        for (int i = tid; i < P / 4; i += 256) {
            uint4 v = x4[i];
            unsigned vv[4] = {v.x, v.y, v.z, v.w};
#pragma unroll
            for (int r = 0; r < 4; r++) {
                int bk = (int)(vv[r] >> 20);
                if (bk > b0) s += (double)__uint_as_float(vv[r]);
                else if (bk == b0) {
                    int pos = atomicAdd(&sscal[2], 1);
                    if (pos < LCAP) slist[pos] = vv[r];
                }
            }
        }
        __syncthreads();
        int lcnt = sscal[2];
        if (Kp0 > 0) {
            if (lcnt <= LCAP) {
                // level 1: bits [9:20)
                for (int i = tid; i < NBKT; i += 256) shist[i] = 0u;
                __syncthreads();
                for (int i = tid; i < lcnt; i += 256)
                    atomicAdd(&shist[(slist[i] >> 9) & 0x7FFu], 1u);
                __syncthreads();
                find_bound(shist, NBKT, Kp0, sscal, wsum, tid);
                int b1 = sscal[0], Kp1 = sscal[1];
                if (tid == 0) sscal[3] = 0;
                __syncthreads();
                for (int i = tid; i < lcnt; i += 256) {
                    unsigned v = slist[i];
                    int sb = (int)((v >> 9) & 0x7FFu);
                    if (sb > b1) s += (double)__uint_as_float(v);
                    else if (sb == b1) list2[atomicAdd(&sscal[3], 1)] = v;
                }
                __syncthreads();
                int n2 = sscal[3];
                // level 2: bits [0:9)
                for (int i = tid; i < 512; i += 256) shist[i] = 0u;
                __syncthreads();
                for (int i = tid; i < n2; i += 256)
                    atomicAdd(&shist[list2[i] & 0x1FFu], 1u);
                __syncthreads();
                find_bound(shist, 512, Kp1, sscal, wsum, tid);
                int b2 = sscal[0], R = sscal[1];
                for (int i = tid; i < n2; i += 256) {
                    unsigned v = list2[i];
                    if ((int)(v & 0x1FFu) > b2) s += (double)__uint_as_float(v);
                }
                unsigned Tbits = ((unsigned)b0 << 20) | ((unsigned)b1 << 9) | (unsigned)b2;
                if (tid == 0) s += (double)R * (double)__uint_as_float(Tbits);
            } else {
                // fallback (never expected): 20-bit binary search over global, bucket-filtered
                const unsigned* src = (const unsigned*)(ce_neg + (size_t)b * P);
                unsigned T = (unsigned)b0 << 20;
                for (int bit = 19; bit >= 0; bit--) {
                    unsigned cand = T | (1u << bit);
                    int cc = 0;
                    for (int i = tid; i < P; i += 256) {
                        unsigned v = src[i];
                        if ((int)(v >> 20) == b0 && v >= cand) cc++;
                    }
                    for (int off = 32; off > 0; off >>= 1) cc += __shfl_down(cc, off, 64);
                    if ((tid & 63) == 0) swi[tid >> 6] = cc;
                    __syncthreads();
                    int tot = swi[0] + swi[1] + swi[2] + swi[3];
                    __syncthreads();
                    if (tot >= Kp0) T = cand;
                }
                int cgt = 0;
                for (int i = tid; i < P; i += 256) {
                    unsigned v = src[i];
                    if ((int)(v >> 20) == b0 && v > T) { cgt++; s += (double)__uint_as_float(v); }
                }
                for (int off = 32; off > 0; off >>= 1) cgt += __shfl_down(cgt, off, 64);
                if ((tid & 63) == 0) swi[tid >> 6] = cgt;
                __syncthreads();
                if (tid == 0) {
                    int cg = swi[0] + swi[1] + swi[2] + swi[3];
                    s += (double)(Kp0 - cg) * (double)__uint_as_float(T);
                }
                __syncthreads();
            }
        }
        for (int off = 32; off > 0; off >>= 1) s += __shfl_down(s, off, 64);
        if ((tid & 63) == 0) swd[tid >> 6] = s;
        __syncthreads();
        if (tid == 0) atomicAdd(&acc[2], swd[0] + swd[1] + swd[2] + swd[3]);
    }

    // ---- global arrival: last of 32 winners writes the outputs ----
    __syncthreads();
    if (tid == 0) {
        __threadfence();
        unsigned old = __hip_atomic_fetch_add(arrv_all, 1u,
                                              __ATOMIC_ACQ_REL, __HIP_MEMORY_SCOPE_AGENT);
        if (old == B - 1) {
            int npt = 0;
            for (int k = 0; k < B; k++)
                npt += __hip_atomic_load(&n_pos[k], __ATOMIC_RELAXED, __HIP_MEMORY_SCOPE_AGENT);
            u64 u0 = __hip_atomic_load((u64*)&acc[0], __ATOMIC_RELAXED, __HIP_MEMORY_SCOPE_AGENT);
            u64 u1 = __hip_atomic_load((u64*)&acc[1], __ATOMIC_RELAXED, __HIP_MEMORY_SCOPE_AGENT);
            u64 u2 = __hip_atomic_load((u64*)&acc[2], __ATOMIC_RELAXED, __HIP_MEMORY_SCOPE_AGENT);
            double a0 = __longlong_as_double((long long)u0);
            double a1 = __longlong_as_double((long long)u1);
            double a2 = __longlong_as_double((long long)u2);
            double npf = (double)npt;
            float conf = (float)((a1 + a2) / npf);
            float loc = 10.0f * (float)(a0 / (npf * 4.0));
            out[0] = conf + loc;
            out[1] = conf;
            out[2] = loc;
        }
    }
}

extern "C" void kernel_launch(void* const* d_in, const int* in_sizes, int n_in,
                              void* d_out, int out_size, void* d_ws, size_t ws_size,
                              hipStream_t stream) {
    const float* pred_cls = (const float*)d_in[0];
    const float* pred_loc = (const float*)d_in[1];
    const float* gt_boxes = (const float*)d_in[2];
    const int*   gt_labels = (const int*)d_in[3];
    const float* anchor   = (const float*)d_in[4];
    float* out = (float*)d_out;
    char* ws = (char*)d_ws;

    k_objmax<<<dim3(16, B), 256, 0, stream>>>(gt_boxes, anchor, ws);
    k_fused<<<24 * B, 256, 0, stream>>>(pred_cls, pred_loc, gt_boxes, gt_labels,
                                        anchor, ws, out);
}

// Round 8
// 350.963 us; speedup vs baseline: 1.0676x; 1.0615x over previous
//
#include <hip/hip_runtime.h>
#include <stdint.h>

#define B 32
#define P 24564      // divisible by 4
#define NCLS 21
#define NOBJ 24
#define THRESH 0.5f
#define NBKT 2048    // level-0/1 histogram buckets
#define LCAP 2816    // LDS candidate-list capacity

// ws layout (bytes)
#define OFF_ACC      0        // double[3]: loc_sum, conf_pos, conf_neg
#define OFF_ARRV     24       // u32: k_sel arrival counter
#define OFF_NPOS     32       // int[B] = 128
#define HDR_WORDS    40       // 160 B header, zeroed by k_objmax block(0,0)
#define OFF_OBJPART  160      // u64[B*NOBJ*16] = 98304 (per-block partials, no init)
#define OFF_HIST     98464    // u32[B*NBKT] = 262144 (zeroed by k_objmax slices)
#define OFF_CENEG    360608   // float[B*P] = 3144192 (16B aligned)

typedef unsigned long long u64;
__device__ __forceinline__ u64 umax64(u64 a, u64 b) { return a > b ? a : b; }

// ---------------- Kernel 1: per-object best-prior partials + ws init -------------------------
__global__ __launch_bounds__(256) void k_objmax(
    const float* __restrict__ gt_boxes, const float* __restrict__ anchor,
    char* __restrict__ ws) {
#pragma clang fp contract(off)
    int b = blockIdx.y;
    int j = blockIdx.x;                       // 0..15
    int tid = threadIdx.x;
    unsigned* hist = (unsigned*)(ws + OFF_HIST);
    u64* part = (u64*)(ws + OFF_OBJPART);
    if (tid < 128) hist[(b * 16 + j) * 128 + tid] = 0u;      // zero hist slice
    if (b == 0 && j == 0 && tid < HDR_WORDS) ((unsigned*)ws)[tid] = 0u;  // zero header
    __shared__ float4 sbox[NOBJ];
    __shared__ u64 sbest[NOBJ];
    if (tid < NOBJ) {
        const float* g = gt_boxes + (size_t)(b * NOBJ + tid) * 4;
        sbox[tid] = make_float4(g[0], g[1], g[2], g[3]);
        sbest[tid] = 0ull;
    }
    __syncthreads();
    u64 best[NOBJ];
#pragma unroll
    for (int n = 0; n < NOBJ; n++) best[n] = 0ull;
    int pend = min(P, (j + 1) * 1536);
    for (int p = j * 1536 + tid; p < pend; p += 256) {
        float4 a = *(const float4*)(anchor + (size_t)p * 4);
        float ax0 = a.x - a.z * 0.5f, ay0 = a.y - a.w * 0.5f;
        float ax1 = a.x + a.z * 0.5f, ay1 = a.y + a.w * 0.5f;
        float area_a = (ax1 - ax0) * (ay1 - ay0);
        unsigned pk = ~(unsigned)p;
#pragma unroll
        for (int n = 0; n < NOBJ; n++) {
            float4 bx = sbox[n];
            float ltx = fmaxf(bx.x, ax0), lty = fmaxf(bx.y, ay0);
            float rbx = fminf(bx.z, ax1), rby = fminf(bx.w, ay1);
            float w = fmaxf(rbx - ltx, 0.f), h = fmaxf(rby - lty, 0.f);
            float inter = w * h;
            float area_o = (bx.z - bx.x) * (bx.w - bx.y);
            float iou = inter / (area_o + area_a - inter);
            u64 key = ((u64)__float_as_uint(iou) << 32) | pk;
            best[n] = umax64(best[n], key);
        }
    }
#pragma unroll
    for (int n = 0; n < NOBJ; n++) {
        u64 v = best[n];
        for (int off = 32; off > 0; off >>= 1) v = umax64(v, __shfl_down(v, off, 64));
        if ((tid & 63) == 0) atomicMax(&sbest[n], v);
    }
    __syncthreads();
    if (tid < NOBJ) part[((size_t)b * NOBJ + tid) * 16 + j] = sbest[tid];  // plain store
}

// ---------------- Kernel 2: fused match + loc-L1 + CE + histogram (register streaming) -------
// 768 blocks = 24/batch; each thread owns 4 consecutive priors (21 aligned float4 loads).
__global__ __launch_bounds__(256, 2) void k_mainB(
    const float* __restrict__ pred_cls, const float* __restrict__ pred_loc,
    const float* __restrict__ gt_boxes, const int* __restrict__ gt_labels,
    const float* __restrict__ anchor, char* __restrict__ ws) {
#pragma clang fp contract(off)
    double* acc = (double*)(ws + OFF_ACC);
    int* n_pos = (int*)(ws + OFF_NPOS);
    const u64* objpart = (const u64*)(ws + OFF_OBJPART);
    unsigned* hist = (unsigned*)(ws + OFF_HIST);
    float* ce_neg = (float*)(ws + OFF_CENEG);

    __shared__ float4 sbox[NOBJ];
    __shared__ int slab[NOBJ];
    __shared__ int sobj[NOBJ];
    __shared__ unsigned shist[NBKT];
    __shared__ float swf[8];
    __shared__ int swi[4];
    const int tid = threadIdx.x;
    const int b = blockIdx.x / 24;
    const int j = blockIdx.x % 24;

    for (int i = tid; i < NBKT; i += 256) shist[i] = 0u;
    if (tid < NOBJ) {
        const float* g = gt_boxes + (size_t)(b * NOBJ + tid) * 4;
        sbox[tid] = make_float4(g[0], g[1], g[2], g[3]);
        slab[tid] = gt_labels[b * NOBJ + tid];
        const u64* pp = objpart + ((size_t)b * NOBJ + tid) * 16;
        u64 m = pp[0];
#pragma unroll
        for (int q = 1; q < 16; q++) m = umax64(m, pp[q]);
        sobj[tid] = (int)(~(unsigned)(m & 0xFFFFFFFFull));
    }
    __syncthreads();

    int p0 = j * 1024 + tid * 4;
    float lsum = 0.f, cpos = 0.f;
    int lnp = 0;
    if (p0 < P) {
        float4 xx[21];
        const float4* xp = (const float4*)(pred_cls + ((size_t)b * P + p0) * NCLS);
#pragma unroll
        for (int k = 0; k < 21; k++) xx[k] = xp[k];
        const float* arr = (const float*)xx;
        float4 anc4[4];
#pragma unroll
        for (int r = 0; r < 4; r++) anc4[r] = ((const float4*)anchor)[p0 + r];
        float4 cev;
        float* cevp = (float*)&cev;
#pragma unroll
        for (int r = 0; r < 4; r++) {
            int p = p0 + r;
            float4 a = anc4[r];
            float ax0 = a.x - a.z * 0.5f, ay0 = a.y - a.w * 0.5f;
            float ax1 = a.x + a.z * 0.5f, ay1 = a.y + a.w * 0.5f;
            float area_a = (ax1 - ax0) * (ay1 - ay0);
            float bv = -1.f;
            int bn = 0;
#pragma unroll
            for (int n = 0; n < NOBJ; n++) {
                float4 bx = sbox[n];
                float ltx = fmaxf(bx.x, ax0), lty = fmaxf(bx.y, ay0);
                float rbx = fminf(bx.z, ax1), rby = fminf(bx.w, ay1);
                float w = fmaxf(rbx - ltx, 0.f), h = fmaxf(rby - lty, 0.f);
                float inter = w * h;
                float area_o = (bx.z - bx.x) * (bx.w - bx.y);
                float iou = inter / (area_o + area_a - inter);
                if (p == sobj[n]) iou = 1.0f;
                if (iou > bv) { bv = iou; bn = n; }
            }
            int pos = (bv >= THRESH) ? 1 : 0;
            int cls = pos ? (slab[bn] + 1) : 0;
            const float* x = arr + r * 21;
            float m = x[0];
#pragma unroll
            for (int q = 1; q < NCLS; q++) m = fmaxf(m, x[q]);
            float s = 0.f;
#pragma unroll
            for (int q = 0; q < NCLS; q++) s += __expf(x[q] - m);
            float xc = x[0];
#pragma unroll
            for (int q = 1; q < NCLS; q++) xc = (cls == q) ? x[q] : xc;
            float ce = m + __logf(s) - xc;
            if (pos) {
                lnp++;
                cpos += ce;
                cevp[r] = 0.f;
                float4 bx = sbox[bn];
                float bcx = (bx.x + bx.z) * 0.5f, bcy = (bx.y + bx.w) * 0.5f;
                float bw = bx.z - bx.x, bh = bx.w - bx.y;
                float t0 = (bcx - a.x) / (a.z / 10.0f);
                float t1 = (bcy - a.y) / (a.w / 10.0f);
                float t2 = __logf(bw / a.z) * 5.0f;
                float t3 = __logf(bh / a.w) * 5.0f;
                float4 pl = *(const float4*)(pred_loc + ((size_t)b * P + p) * 4);
                lsum += fabsf(pl.x - t0) + fabsf(pl.y - t1) + fabsf(pl.z - t2) + fabsf(pl.w - t3);
            } else {
                float cen = fmaxf(ce, 0.f);   // keep sign bit out of bucket bits
                cevp[r] = cen;
                atomicAdd(&shist[__float_as_uint(cen) >> 20], 1u);
            }
        }
        *(float4*)(ce_neg + (size_t)b * P + p0) = cev;
    }
    for (int off = 32; off > 0; off >>= 1) {
        lsum += __shfl_down(lsum, off, 64);
        cpos += __shfl_down(cpos, off, 64);
        lnp  += __shfl_down(lnp, off, 64);
    }
    if ((tid & 63) == 0) { swf[tid >> 6] = lsum; swf[4 + (tid >> 6)] = cpos; swi[tid >> 6] = lnp; }
    __syncthreads();
    if (tid == 0) {
        float ls = swf[0] + swf[1] + swf[2] + swf[3];
        float cs = swf[4] + swf[5] + swf[6] + swf[7];
        int np = swi[0] + swi[1] + swi[2] + swi[3];
        if (np) atomicAdd(&n_pos[b], np);
        atomicAdd(&acc[0], (double)ls);
        atomicAdd(&acc[1], (double)cs);
    }
    for (int i = tid; i < NBKT; i += 256) {
        unsigned c = shist[i];
        if (c) atomicAdd(&hist[b * NBKT + i], c);
    }
}

// ---- parallel boundary-bucket find: suffix-scan of shist[NB], writes sscal[0]=bkt, [1]=resid
__device__ __forceinline__ void find_bound(const unsigned* shist, int NB, int K,
                                           int* sscal, unsigned* wsum, int tid) {
    int G = NB >> 8;
    unsigned loc[8];
    unsigned tot = 0;
    for (int g = 0; g < G; g++) { loc[g] = shist[tid * G + g]; tot += loc[g]; }
    unsigned v = tot;
    int lane = tid & 63;
    for (int off = 1; off < 64; off <<= 1) {
        unsigned o = __shfl_down(v, off, 64);
        if (lane + off < 64) v += o;     // v = inclusive suffix within wave
    }
    if (lane == 0) wsum[tid >> 6] = v;
    __syncthreads();
    unsigned above = 0;
    for (int w = (tid >> 6) + 1; w < 4; w++) above += wsum[w];
    unsigned sfx_excl = above + (v - tot);   // suffix over threads > tid
    unsigned snext = 0, sloc = 0;
    for (int k = G - 1; k >= 0; k--) {
        sloc = snext + loc[k];
        unsigned sfx_i = sloc + sfx_excl;
        unsigned sfx_n = snext + sfx_excl;
        if (sfx_i >= (unsigned)K && sfx_n < (unsigned)K) {
            sscal[0] = tid * G + k;
            sscal[1] = K - (int)sfx_n;
        }
        snext = sloc;
    }
    if (tid == 0) {
        unsigned total = sloc + sfx_excl;
        if (total < (unsigned)K) {        // take everything + zero padding
            sscal[0] = 0;
            sscal[1] = K - (int)((sloc - loc[0]) + sfx_excl);
        }
    }
    __syncthreads();
}

// ---------------- Kernel 3: top-K sum via 3-level radix refine + final scalars ---------------
__global__ __launch_bounds__(256) void k_sel(
    const float* __restrict__ ce_neg, const unsigned* __restrict__ hist,
    const int* __restrict__ n_pos, double* __restrict__ acc,
    unsigned* __restrict__ arrv, float* __restrict__ out) {
    __shared__ unsigned shist[NBKT];     // reused per level
    __shared__ unsigned slist[LCAP];
    __shared__ unsigned list2[LCAP];
    __shared__ int swi[4];
    __shared__ double swd[4];
    __shared__ unsigned wsum[4];
    __shared__ int sscal[4];             // [0]=bkt [1]=resid [2]=cnt1 [3]=cnt2
    const int b = blockIdx.x;
    const int tid = threadIdx.x;
    const int lane = tid & 63;
    int K = n_pos[b] * 3;
    if (K > P) K = P;
    double s = 0.0;
    if (K > 0) {
        for (int i = tid; i < NBKT; i += 256) shist[i] = hist[b * NBKT + i];
        __syncthreads();
        find_bound(shist, NBKT, K, sscal, wsum, tid);
        int b0 = sscal[0], Kp0 = sscal[1];
        if (tid == 0) { sscal[2] = 0; sscal[3] = 0; }
        __syncthreads();
        // single pass: sum strictly-above buckets, wave-aggregated compact of boundary bucket
        const uint4* x4 = (const uint4*)(ce_neg + (size_t)b * P);
        for (int i = tid; i < P / 4; i += 256) {
            uint4 v = x4[i];
            unsigned vv[4] = {v.x, v.y, v.z, v.w};
#pragma unroll
            for (int r = 0; r < 4; r++) {
                int bk = (int)(vv[r] >> 20);
                if (bk > b0) s += (double)__uint_as_float(vv[r]);
                bool eq = (bk == b0);
                u64 mask = __ballot(eq);
                if (mask) {
                    int leader = (int)(__ffsll((long long)mask) - 1);
                    int base = 0;
                    if (eq && lane == leader) base = atomicAdd(&sscal[2], (int)__popcll(mask));
                    base = __shfl(base, leader, 64);
                    if (eq) {
                        int pos = base + (int)__popcll(mask & ((1ull << lane) - 1ull));
                        if (pos < LCAP) slist[pos] = vv[r];
                    }
                }
            }
        }
        __syncthreads();
        int lcnt = sscal[2];
        if (Kp0 > 0) {
            if (lcnt <= LCAP) {
                // level 1: bits [9:20)
                for (int i = tid; i < NBKT; i += 256) shist[i] = 0u;
                __syncthreads();
                for (int i = tid; i < lcnt; i += 256)
                    atomicAdd(&shist[(slist[i] >> 9) & 0x7FFu], 1u);
                __syncthreads();
                find_bound(shist, NBKT, Kp0, sscal, wsum, tid);
                int b1 = sscal[0], Kp1 = sscal[1];
                __syncthreads();
                for (int i = tid; i < lcnt; i += 256) {
                    unsigned v = slist[i];
                    int sb = (int)((v >> 9) & 0x7FFu);
                    if (sb > b1) s += (double)__uint_as_float(v);
                    else if (sb == b1) list2[atomicAdd(&sscal[3], 1)] = v;
                }
                __syncthreads();
                int n2 = sscal[3];
                // level 2: bits [0:9)
                for (int i = tid; i < 512; i += 256) shist[i] = 0u;
                __syncthreads();
                for (int i = tid; i < n2; i += 256)
                    atomicAdd(&shist[list2[i] & 0x1FFu], 1u);
                __syncthreads();
                find_bound(shist, 512, Kp1, sscal, wsum, tid);
                int b2 = sscal[0], R = sscal[1];
                for (int i = tid; i < n2; i += 256) {
                    unsigned v = list2[i];
                    if ((int)(v & 0x1FFu) > b2) s += (double)__uint_as_float(v);
                }
                unsigned Tbits = ((unsigned)b0 << 20) | ((unsigned)b1 << 9) | (unsigned)b2;
                if (tid == 0) s += (double)R * (double)__uint_as_float(Tbits);
            } else {
                // fallback (never expected): 20-bit binary search, bucket-filtered
                const unsigned* src = (const unsigned*)(ce_neg + (size_t)b * P);
                unsigned T = (unsigned)b0 << 20;
                for (int bit = 19; bit >= 0; bit--) {
                    unsigned cand = T | (1u << bit);
                    int cc = 0;
                    for (int i = tid; i < P; i += 256) {
                        unsigned v = src[i];
                        if ((int)(v >> 20) == b0 && v >= cand) cc++;
                    }
                    for (int off = 32; off > 0; off >>= 1) cc += __shfl_down(cc, off, 64);
                    if (lane == 0) swi[tid >> 6] = cc;
                    __syncthreads();
                    int tot = swi[0] + swi[1] + swi[2] + swi[3];
                    __syncthreads();
                    if (tot >= Kp0) T = cand;
                }
                int cgt = 0;
                for (int i = tid; i < P; i += 256) {
                    unsigned v = src[i];
                    if ((int)(v >> 20) == b0 && v > T) { cgt++; s += (double)__uint_as_float(v); }
                }
                for (int off = 32; off > 0; off >>= 1) cgt += __shfl_down(cgt, off, 64);
                if (lane == 0) swi[tid >> 6] = cgt;
                __syncthreads();
                if (tid == 0) {
                    int cg = swi[0] + swi[1] + swi[2] + swi[3];
                    s += (double)(Kp0 - cg) * (double)__uint_as_float(T);
                }
                __syncthreads();
            }
        }
        for (int off = 32; off > 0; off >>= 1) s += __shfl_down(s, off, 64);
        if (lane == 0) swd[tid >> 6] = s;
        __syncthreads();
        if (tid == 0) atomicAdd(&acc[2], swd[0] + swd[1] + swd[2] + swd[3]);
    }
    // ---- arrival: last block writes the outputs (R5-verified pattern, no spinning) ----
    __syncthreads();
    if (tid == 0) {
        __threadfence();
        unsigned done = __hip_atomic_fetch_add(arrv, 1u, __ATOMIC_ACQ_REL,
                                               __HIP_MEMORY_SCOPE_AGENT);
        if (done == B - 1) {
            int npt = 0;
            for (int k = 0; k < B; k++)
                npt += __hip_atomic_load((int*)&n_pos[k], __ATOMIC_RELAXED,
                                         __HIP_MEMORY_SCOPE_AGENT);
            u64 u0 = __hip_atomic_load((u64*)&acc[0], __ATOMIC_RELAXED, __HIP_MEMORY_SCOPE_AGENT);
            u64 u1 = __hip_atomic_load((u64*)&acc[1], __ATOMIC_RELAXED, __HIP_MEMORY_SCOPE_AGENT);
            u64 u2 = __hip_atomic_load((u64*)&acc[2], __ATOMIC_RELAXED, __HIP_MEMORY_SCOPE_AGENT);
            double a0 = __longlong_as_double((long long)u0);
            double a1 = __longlong_as_double((long long)u1);
            double a2 = __longlong_as_double((long long)u2);
            double npf = (double)npt;
            float conf = (float)((a1 + a2) / npf);
            float loc = 10.0f * (float)(a0 / (npf * 4.0));
            out[0] = conf + loc;
            out[1] = conf;
            out[2] = loc;
        }
    }
}

extern "C" void kernel_launch(void* const* d_in, const int* in_sizes, int n_in,
                              void* d_out, int out_size, void* d_ws, size_t ws_size,
                              hipStream_t stream) {
    const float* pred_cls = (const float*)d_in[0];
    const float* pred_loc = (const float*)d_in[1];
    const float* gt_boxes = (const float*)d_in[2];
    const int*   gt_labels = (const int*)d_in[3];
    const float* anchor   = (const float*)d_in[4];
    float* out = (float*)d_out;
    char* ws = (char*)d_ws;
    double* acc = (double*)(ws + OFF_ACC);
    unsigned* arrv = (unsigned*)(ws + OFF_ARRV);
    int* n_pos = (int*)(ws + OFF_NPOS);
    unsigned* hist = (unsigned*)(ws + OFF_HIST);
    float* ce_neg = (float*)(ws + OFF_CENEG);

    k_objmax<<<dim3(16, B), 256, 0, stream>>>(gt_boxes, anchor, ws);
    k_mainB<<<24 * B, 256, 0, stream>>>(pred_cls, pred_loc, gt_boxes, gt_labels, anchor, ws);
    k_sel<<<B, 256, 0, stream>>>(ce_neg, hist, n_pos, acc, arrv, out);
}

// Round 9
// 180.192 us; speedup vs baseline: 2.0794x; 1.9477x over previous
//
#include <hip/hip_runtime.h>
#include <stdint.h>

#define B 32
#define P 24564      // divisible by 4
#define NCLS 21
#define NOBJ 24
#define THRESH 0.5f
#define NBKT 2048    // level-0/1 histogram buckets
#define LCAP 6144    // LDS candidate-list capacity
#define BKT_BASE 7232   // 113 << 6 : bucket = (bits>>17) - BKT_BASE, exp range [113,145)

// ws layout (bytes)
#define OFF_ACC      0        // double[3]: loc_sum, conf_pos, conf_neg
#define OFF_ARRV     24       // u32: k_sel arrival counter
#define OFF_NPOS     32       // int[B] = 128
#define HDR_WORDS    40       // 160 B header, zeroed by k_objmax block(0,0)
#define OFF_OBJPART  160      // u64[B*NOBJ*16] = 98304 (per-block partials, no init)
#define OFF_HIST     98464    // u32[B*NBKT] = 262144 (zeroed by k_objmax slices)
#define OFF_CENEG    360608   // float[B*P] = 3144192 (16B aligned)

typedef unsigned long long u64;
__device__ __forceinline__ u64 umax64(u64 a, u64 b) { return a > b ? a : b; }

// bucket map: 8-bit exponent + 6 mantissa bits, clamped. 64 sub-buckets per binade ->
// boundary bucket holds ~hundreds, not thousands (fixes R6-R8's 190us fallback storm).
__device__ __forceinline__ int ce_bucket(unsigned bits) {
    int bk = (int)(bits >> 17) - BKT_BASE;
    return bk < 0 ? 0 : (bk > 2047 ? 2047 : bk);
}

// ---------------- Kernel 1: per-object best-prior partials + ws init -------------------------
__global__ __launch_bounds__(256) void k_objmax(
    const float* __restrict__ gt_boxes, const float* __restrict__ anchor,
    char* __restrict__ ws) {
#pragma clang fp contract(off)
    int b = blockIdx.y;
    int j = blockIdx.x;                       // 0..15
    int tid = threadIdx.x;
    unsigned* hist = (unsigned*)(ws + OFF_HIST);
    u64* part = (u64*)(ws + OFF_OBJPART);
    if (tid < 128) hist[(b * 16 + j) * 128 + tid] = 0u;      // zero hist slice
    if (b == 0 && j == 0 && tid < HDR_WORDS) ((unsigned*)ws)[tid] = 0u;  // zero header
    __shared__ float4 sbox[NOBJ];
    __shared__ u64 sbest[NOBJ];
    if (tid < NOBJ) {
        const float* g = gt_boxes + (size_t)(b * NOBJ + tid) * 4;
        sbox[tid] = make_float4(g[0], g[1], g[2], g[3]);
        sbest[tid] = 0ull;
    }
    __syncthreads();
    u64 best[NOBJ];
#pragma unroll
    for (int n = 0; n < NOBJ; n++) best[n] = 0ull;
    int pend = min(P, (j + 1) * 1536);
    for (int p = j * 1536 + tid; p < pend; p += 256) {
        float4 a = *(const float4*)(anchor + (size_t)p * 4);
        float ax0 = a.x - a.z * 0.5f, ay0 = a.y - a.w * 0.5f;
        float ax1 = a.x + a.z * 0.5f, ay1 = a.y + a.w * 0.5f;
        float area_a = (ax1 - ax0) * (ay1 - ay0);
        unsigned pk = ~(unsigned)p;
#pragma unroll
        for (int n = 0; n < NOBJ; n++) {
            float4 bx = sbox[n];
            float ltx = fmaxf(bx.x, ax0), lty = fmaxf(bx.y, ay0);
            float rbx = fminf(bx.z, ax1), rby = fminf(bx.w, ay1);
            float w = fmaxf(rbx - ltx, 0.f), h = fmaxf(rby - lty, 0.f);
            float inter = w * h;
            float area_o = (bx.z - bx.x) * (bx.w - bx.y);
            float iou = inter / (area_o + area_a - inter);
            u64 key = ((u64)__float_as_uint(iou) << 32) | pk;
            best[n] = umax64(best[n], key);
        }
    }
#pragma unroll
    for (int n = 0; n < NOBJ; n++) {
        u64 v = best[n];
        for (int off = 32; off > 0; off >>= 1) v = umax64(v, __shfl_down(v, off, 64));
        if ((tid & 63) == 0) atomicMax(&sbest[n], v);
    }
    __syncthreads();
    if (tid < NOBJ) part[((size_t)b * NOBJ + tid) * 16 + j] = sbest[tid];  // plain store
}

// ---------------- Kernel 2: fused match + loc-L1 + CE + histogram (register streaming) -------
__global__ __launch_bounds__(256, 2) void k_mainB(
    const float* __restrict__ pred_cls, const float* __restrict__ pred_loc,
    const float* __restrict__ gt_boxes, const int* __restrict__ gt_labels,
    const float* __restrict__ anchor, char* __restrict__ ws) {
#pragma clang fp contract(off)
    double* acc = (double*)(ws + OFF_ACC);
    int* n_pos = (int*)(ws + OFF_NPOS);
    const u64* objpart = (const u64*)(ws + OFF_OBJPART);
    unsigned* hist = (unsigned*)(ws + OFF_HIST);
    float* ce_neg = (float*)(ws + OFF_CENEG);

    __shared__ float4 sbox[NOBJ];
    __shared__ int slab[NOBJ];
    __shared__ int sobj[NOBJ];
    __shared__ unsigned shist[NBKT];
    __shared__ float swf[8];
    __shared__ int swi[4];
    const int tid = threadIdx.x;
    const int b = blockIdx.x / 24;
    const int j = blockIdx.x % 24;

    for (int i = tid; i < NBKT; i += 256) shist[i] = 0u;
    if (tid < NOBJ) {
        const float* g = gt_boxes + (size_t)(b * NOBJ + tid) * 4;
        sbox[tid] = make_float4(g[0], g[1], g[2], g[3]);
        slab[tid] = gt_labels[b * NOBJ + tid];
        const u64* pp = objpart + ((size_t)b * NOBJ + tid) * 16;
        u64 m = pp[0];
#pragma unroll
        for (int q = 1; q < 16; q++) m = umax64(m, pp[q]);
        sobj[tid] = (int)(~(unsigned)(m & 0xFFFFFFFFull));
    }
    __syncthreads();

    int p0 = j * 1024 + tid * 4;
    float lsum = 0.f, cpos = 0.f;
    int lnp = 0;
    if (p0 < P) {
        float4 xx[21];
        const float4* xp = (const float4*)(pred_cls + ((size_t)b * P + p0) * NCLS);
#pragma unroll
        for (int k = 0; k < 21; k++) xx[k] = xp[k];
        const float* arr = (const float*)xx;
        float4 anc4[4];
#pragma unroll
        for (int r = 0; r < 4; r++) anc4[r] = ((const float4*)anchor)[p0 + r];
        float4 cev;
        float* cevp = (float*)&cev;
#pragma unroll
        for (int r = 0; r < 4; r++) {
            int p = p0 + r;
            float4 a = anc4[r];
            float ax0 = a.x - a.z * 0.5f, ay0 = a.y - a.w * 0.5f;
            float ax1 = a.x + a.z * 0.5f, ay1 = a.y + a.w * 0.5f;
            float area_a = (ax1 - ax0) * (ay1 - ay0);
            float bv = -1.f;
            int bn = 0;
#pragma unroll
            for (int n = 0; n < NOBJ; n++) {
                float4 bx = sbox[n];
                float ltx = fmaxf(bx.x, ax0), lty = fmaxf(bx.y, ay0);
                float rbx = fminf(bx.z, ax1), rby = fminf(bx.w, ay1);
                float w = fmaxf(rbx - ltx, 0.f), h = fmaxf(rby - lty, 0.f);
                float inter = w * h;
                float area_o = (bx.z - bx.x) * (bx.w - bx.y);
                float iou = inter / (area_o + area_a - inter);
                if (p == sobj[n]) iou = 1.0f;
                if (iou > bv) { bv = iou; bn = n; }
            }
            int pos = (bv >= THRESH) ? 1 : 0;
            int cls = pos ? (slab[bn] + 1) : 0;
            const float* x = arr + r * 21;
            float m = x[0];
#pragma unroll
            for (int q = 1; q < NCLS; q++) m = fmaxf(m, x[q]);
            float s = 0.f;
#pragma unroll
            for (int q = 0; q < NCLS; q++) s += __expf(x[q] - m);
            float xc = x[0];
#pragma unroll
            for (int q = 1; q < NCLS; q++) xc = (cls == q) ? x[q] : xc;
            float ce = m + __logf(s) - xc;
            if (pos) {
                lnp++;
                cpos += ce;
                cevp[r] = 0.f;
                float4 bx = sbox[bn];
                float bcx = (bx.x + bx.z) * 0.5f, bcy = (bx.y + bx.w) * 0.5f;
                float bw = bx.z - bx.x, bh = bx.w - bx.y;
                float t0 = (bcx - a.x) / (a.z / 10.0f);
                float t1 = (bcy - a.y) / (a.w / 10.0f);
                float t2 = __logf(bw / a.z) * 5.0f;
                float t3 = __logf(bh / a.w) * 5.0f;
                float4 pl = *(const float4*)(pred_loc + ((size_t)b * P + p) * 4);
                lsum += fabsf(pl.x - t0) + fabsf(pl.y - t1) + fabsf(pl.z - t2) + fabsf(pl.w - t3);
            } else {
                float cen = fmaxf(ce, 0.f);   // keep sign bit out of bucket bits
                cevp[r] = cen;
                atomicAdd(&shist[ce_bucket(__float_as_uint(cen))], 1u);
            }
        }
        *(float4*)(ce_neg + (size_t)b * P + p0) = cev;
    }
    for (int off = 32; off > 0; off >>= 1) {
        lsum += __shfl_down(lsum, off, 64);
        cpos += __shfl_down(cpos, off, 64);
        lnp  += __shfl_down(lnp, off, 64);
    }
    if ((tid & 63) == 0) { swf[tid >> 6] = lsum; swf[4 + (tid >> 6)] = cpos; swi[tid >> 6] = lnp; }
    __syncthreads();
    if (tid == 0) {
        float ls = swf[0] + swf[1] + swf[2] + swf[3];
        float cs = swf[4] + swf[5] + swf[6] + swf[7];
        int np = swi[0] + swi[1] + swi[2] + swi[3];
        if (np) atomicAdd(&n_pos[b], np);
        atomicAdd(&acc[0], (double)ls);
        atomicAdd(&acc[1], (double)cs);
    }
    for (int i = tid; i < NBKT; i += 256) {
        unsigned c = shist[i];
        if (c) atomicAdd(&hist[b * NBKT + i], c);
    }
}

// ---- parallel boundary-bucket find: suffix-scan of shist[NB], writes sscal[0]=bkt, [1]=resid
__device__ __forceinline__ void find_bound(const unsigned* shist, int NB, int K,
                                           int* sscal, unsigned* wsum, int tid) {
    int G = NB >> 8;
    unsigned loc[8];
    unsigned tot = 0;
    for (int g = 0; g < G; g++) { loc[g] = shist[tid * G + g]; tot += loc[g]; }
    unsigned v = tot;
    int lane = tid & 63;
    for (int off = 1; off < 64; off <<= 1) {
        unsigned o = __shfl_down(v, off, 64);
        if (lane + off < 64) v += o;     // inclusive suffix within wave
    }
    if (lane == 0) wsum[tid >> 6] = v;
    __syncthreads();
    unsigned above = 0;
    for (int w = (tid >> 6) + 1; w < 4; w++) above += wsum[w];
    unsigned sfx_excl = above + (v - tot);   // suffix over threads > tid
    unsigned snext = 0, sloc = 0;
    for (int k = G - 1; k >= 0; k--) {
        sloc = snext + loc[k];
        unsigned sfx_i = sloc + sfx_excl;
        unsigned sfx_n = snext + sfx_excl;
        if (sfx_i >= (unsigned)K && sfx_n < (unsigned)K) {
            sscal[0] = tid * G + k;
            sscal[1] = K - (int)sfx_n;
        }
        snext = sloc;
    }
    if (tid == 0) {
        unsigned total = sloc + sfx_excl;
        if (total < (unsigned)K) {        // take everything + zero padding
            sscal[0] = 0;
            sscal[1] = K - (int)((sloc - loc[0]) + sfx_excl);
        }
    }
    __syncthreads();
}

// single-wave version for 64 buckets (level 2)
__device__ __forceinline__ void find_bound64(const unsigned* h64, int K, int* sscal, int tid) {
    if (tid < 64) {
        unsigned cnt = h64[tid];
        unsigned v = cnt;
        for (int off = 1; off < 64; off <<= 1) {
            unsigned o = __shfl_down(v, off, 64);
            if (tid + off < 64) v += o;
        }
        unsigned vnext = v - cnt;
        if (v >= (unsigned)K && vnext < (unsigned)K) { sscal[0] = tid; sscal[1] = K - (int)vnext; }
    }
    __syncthreads();
}

// ---------------- Kernel 3: top-K sum via fine radix refine + final scalars ------------------
__global__ __launch_bounds__(256) void k_sel(
    const float* __restrict__ ce_neg, const unsigned* __restrict__ hist,
    const int* __restrict__ n_pos, double* __restrict__ acc,
    unsigned* __restrict__ arrv, float* __restrict__ out) {
    __shared__ unsigned shist[NBKT];     // reused per level
    __shared__ unsigned slist[LCAP];
    __shared__ int swi[4];
    __shared__ double swd[4];
    __shared__ unsigned wsum[4];
    __shared__ int sscal[4];             // [0]=bkt [1]=resid [2]=lcnt
    const int b = blockIdx.x;
    const int tid = threadIdx.x;
    const int lane = tid & 63;
    int K = n_pos[b] * 3;
    if (K > P) K = P;
    double s = 0.0;
    if (K > 0) {
        for (int i = tid; i < NBKT; i += 256) shist[i] = hist[b * NBKT + i];
        __syncthreads();
        find_bound(shist, NBKT, K, sscal, wsum, tid);
        int b0 = sscal[0], Kp0 = sscal[1];
        if (tid == 0) sscal[2] = 0;
        __syncthreads();
        // one pass: sum strictly-above buckets, compact boundary bucket to LDS
        const uint4* x4 = (const uint4*)(ce_neg + (size_t)b * P);
        for (int i = tid; i < P / 4; i += 256) {
            uint4 v = x4[i];
            unsigned vv[4] = {v.x, v.y, v.z, v.w};
#pragma unroll
            for (int r = 0; r < 4; r++) {
                int bk = ce_bucket(vv[r]);
                if (bk > b0) s += (double)__uint_as_float(vv[r]);
                else if (bk == b0) {
                    int pos = atomicAdd(&sscal[2], 1);
                    if (pos < LCAP) slist[pos] = vv[r];
                }
            }
        }
        __syncthreads();
        int lcnt = sscal[2];
        if (Kp0 > 0) {
            bool clamped = (b0 == 0) || (b0 == 2047);
            if (lcnt <= LCAP && !clamped) {
                // ---- level 1: bits [6..17) (monotone within non-clamped level-0 bucket) ----
                for (int i = tid; i < NBKT; i += 256) shist[i] = 0u;
                __syncthreads();
                for (int i = tid; i < lcnt; i += 256)
                    atomicAdd(&shist[(slist[i] >> 6) & 0x7FFu], 1u);
                __syncthreads();
                find_bound(shist, NBKT, Kp0, sscal, wsum, tid);
                int b1 = sscal[0], Kp1 = sscal[1];
                // ---- level 2: bits [0..6), histogram directly from slist (no list2) ----
                if (tid < 64) shist[tid] = 0u;
                __syncthreads();
                for (int i = tid; i < lcnt; i += 256) {
                    unsigned v = slist[i];
                    int k1 = (int)((v >> 6) & 0x7FFu);
                    if (k1 > b1) s += (double)__uint_as_float(v);
                    else if (k1 == b1) atomicAdd(&shist[v & 0x3Fu], 1u);
                }
                __syncthreads();
                find_bound64(shist, Kp1, sscal, tid);
                int b2 = sscal[0], R = sscal[1];
                for (int i = tid; i < lcnt; i += 256) {
                    unsigned v = slist[i];
                    if ((int)((v >> 6) & 0x7FFu) == b1 && (int)(v & 0x3Fu) > b2)
                        s += (double)__uint_as_float(v);
                }
                unsigned Tbits = ((unsigned)(b0 + BKT_BASE) << 17) | ((unsigned)b1 << 6) | (unsigned)b2;
                if (tid == 0) s += (double)R * (double)__uint_as_float(Tbits);
            } else if (lcnt <= LCAP) {
                // clamped boundary bucket (mixed exponents): exact 31-bit search over LDS list
                unsigned T = 0;
                for (int bit = 30; bit >= 0; bit--) {
                    unsigned cand = T | (1u << bit);
                    int cc = 0;
                    for (int i = tid; i < lcnt; i += 256) cc += (slist[i] >= cand) ? 1 : 0;
                    for (int off = 32; off > 0; off >>= 1) cc += __shfl_down(cc, off, 64);
                    if (lane == 0) swi[tid >> 6] = cc;
                    __syncthreads();
                    int tot = swi[0] + swi[1] + swi[2] + swi[3];
                    __syncthreads();
                    if (tot >= Kp0) T = cand;
                }
                int cgt = 0;
                for (int i = tid; i < lcnt; i += 256) {
                    unsigned v = slist[i];
                    if (v > T) { cgt++; s += (double)__uint_as_float(v); }
                }
                for (int off = 32; off > 0; off >>= 1) cgt += __shfl_down(cgt, off, 64);
                if (lane == 0) swi[tid >> 6] = cgt;
                __syncthreads();
                if (tid == 0) {
                    int cg = swi[0] + swi[1] + swi[2] + swi[3];
                    s += (double)(Kp0 - cg) * (double)__uint_as_float(T);
                }
                __syncthreads();
            } else {
                // overflow fallback (not expected): 31-bit search over global, bucket-filtered
                const unsigned* src = (const unsigned*)(ce_neg + (size_t)b * P);
                unsigned T = 0;
                for (int bit = 30; bit >= 0; bit--) {
                    unsigned cand = T | (1u << bit);
                    int cc = 0;
                    for (int i = tid; i < P; i += 256) {
                        unsigned v = src[i];
                        if (ce_bucket(v) == b0 && v >= cand) cc++;
                    }
                    for (int off = 32; off > 0; off >>= 1) cc += __shfl_down(cc, off, 64);
                    if (lane == 0) swi[tid >> 6] = cc;
                    __syncthreads();
                    int tot = swi[0] + swi[1] + swi[2] + swi[3];
                    __syncthreads();
                    if (tot >= Kp0) T = cand;
                }
                int cgt = 0;
                for (int i = tid; i < P; i += 256) {
                    unsigned v = src[i];
                    if (ce_bucket(v) == b0 && v > T) { cgt++; s += (double)__uint_as_float(v); }
                }
                for (int off = 32; off > 0; off >>= 1) cgt += __shfl_down(cgt, off, 64);
                if (lane == 0) swi[tid >> 6] = cgt;
                __syncthreads();
                if (tid == 0) {
                    int cg = swi[0] + swi[1] + swi[2] + swi[3];
                    s += (double)(Kp0 - cg) * (double)__uint_as_float(T);
                }
                __syncthreads();
            }
        }
        for (int off = 32; off > 0; off >>= 1) s += __shfl_down(s, off, 64);
        if (lane == 0) swd[tid >> 6] = s;
        __syncthreads();
        if (tid == 0) atomicAdd(&acc[2], swd[0] + swd[1] + swd[2] + swd[3]);
    }
    // ---- arrival: last block writes the outputs (R5-verified pattern, no spinning) ----
    __syncthreads();
    if (tid == 0) {
        __threadfence();
        unsigned done = __hip_atomic_fetch_add(arrv, 1u, __ATOMIC_ACQ_REL,
                                               __HIP_MEMORY_SCOPE_AGENT);
        if (done == B - 1) {
            int npt = 0;
            for (int k = 0; k < B; k++)
                npt += __hip_atomic_load((int*)&n_pos[k], __ATOMIC_RELAXED,
                                         __HIP_MEMORY_SCOPE_AGENT);
            u64 u0 = __hip_atomic_load((u64*)&acc[0], __ATOMIC_RELAXED, __HIP_MEMORY_SCOPE_AGENT);
            u64 u1 = __hip_atomic_load((u64*)&acc[1], __ATOMIC_RELAXED, __HIP_MEMORY_SCOPE_AGENT);
            u64 u2 = __hip_atomic_load((u64*)&acc[2], __ATOMIC_RELAXED, __HIP_MEMORY_SCOPE_AGENT);
            double a0 = __longlong_as_double((long long)u0);
            double a1 = __longlong_as_double((long long)u1);
            double a2 = __longlong_as_double((long long)u2);
            double npf = (double)npt;
            float conf = (float)((a1 + a2) / npf);
            float loc = 10.0f * (float)(a0 / (npf * 4.0));
            out[0] = conf + loc;
            out[1] = conf;
            out[2] = loc;
        }
    }
}

extern "C" void kernel_launch(void* const* d_in, const int* in_sizes, int n_in,
                              void* d_out, int out_size, void* d_ws, size_t ws_size,
                              hipStream_t stream) {
    const float* pred_cls = (const float*)d_in[0];
    const float* pred_loc = (const float*)d_in[1];
    const float* gt_boxes = (const float*)d_in[2];
    const int*   gt_labels = (const int*)d_in[3];
    const float* anchor   = (const float*)d_in[4];
    float* out = (float*)d_out;
    char* ws = (char*)d_ws;
    double* acc = (double*)(ws + OFF_ACC);
    unsigned* arrv = (unsigned*)(ws + OFF_ARRV);
    int* n_pos = (int*)(ws + OFF_NPOS);
    unsigned* hist = (unsigned*)(ws + OFF_HIST);
    float* ce_neg = (float*)(ws + OFF_CENEG);

    k_objmax<<<dim3(16, B), 256, 0, stream>>>(gt_boxes, anchor, ws);
    k_mainB<<<24 * B, 256, 0, stream>>>(pred_cls, pred_loc, gt_boxes, gt_labels, anchor, ws);
    k_sel<<<B, 256, 0, stream>>>(ce_neg, hist, n_pos, acc, arrv, out);
}